// Round 5
// baseline (465.680 us; speedup 1.0000x reference)
//
#include <hip/hip_runtime.h>
#include <stdint.h>

typedef float f4_t __attribute__((ext_vector_type(4)));
typedef __bf16 bf8_t __attribute__((ext_vector_type(8)));
typedef unsigned short us4_t __attribute__((ext_vector_type(4)));
typedef unsigned short us8_t __attribute__((ext_vector_type(8)));

static __device__ __forceinline__ unsigned short fbf(float f) {
    __bf16 b = (__bf16)f;
    return *(unsigned short*)&b;
}
static __device__ __forceinline__ float bf2f(unsigned short u) {
    union { uint32_t u; float f; } v; v.u = ((uint32_t)u) << 16;
    return v.f;
}
static __device__ __forceinline__ f4_t mfma16(bf8_t a, bf8_t b, f4_t c) {
    return __builtin_amdgcn_mfma_f32_16x16x32_bf16(a, b, c, 0, 0, 0);
}
static __device__ __forceinline__ float sigf(float x) {
    return 1.0f / (1.0f + __expf(-x));
}

// ---------------- kernel 0: convert x/h/W to bf16, build q-normalized x ----
__global__ __launch_bounds__(256) void k_convert(
    const float* __restrict__ x, const float* __restrict__ h,
    const float* __restrict__ W1, const float* __restrict__ W2,
    unsigned short* __restrict__ qn, unsigned short* __restrict__ xb,
    unsigned short* __restrict__ hb, unsigned short* __restrict__ w1b,
    unsigned short* __restrict__ w2b)
{
    __shared__ float sred[4];
    int bid = blockIdx.x, t = threadIdx.x;
    if (bid < 256) {
        float v = x[bid * 256 + t];
        float ss = v * v;
        #pragma unroll
        for (int m = 1; m < 64; m <<= 1) ss += __shfl_xor(ss, m, 64);
        if ((t & 63) == 0) sred[t >> 6] = ss;
        __syncthreads();
        float tot = sred[0] + sred[1] + sred[2] + sred[3];
        float rn = 1.0f / fmaxf(sqrtf(tot), 1e-8f);
        xb[bid * 256 + t] = fbf(v);
        qn[bid * 256 + t] = fbf(v * rn);
    } else if (bid < 512) {
        int b = bid - 256;
        hb[b * 256 + t] = fbf(h[b * 256 + t]);
    } else {
        int i0 = (bid - 512) * 256 + t;
        for (int i = i0; i < 1280 * 256; i += 512 * 256) {
            w1b[i] = fbf(W1[i]);
            w2b[i] = fbf(W2[i]);
        }
    }
}

// ---------------- kernel 1: preact = x@W1^T + h@W2^T + b1 + b2 --------------
__global__ __launch_bounds__(256) void k_gates(
    const unsigned short* __restrict__ xb, const unsigned short* __restrict__ hb,
    const unsigned short* __restrict__ w1b, const unsigned short* __restrict__ w2b,
    const float* __restrict__ b1, const float* __restrict__ b2,
    float* __restrict__ pre)
{
    int bb = (blockIdx.x & 3) * 64;
    int gb = (blockIdx.x >> 2) * 64;
    int t = threadIdx.x, w = t >> 6, lane = t & 63;
    int l15 = lane & 15, q8 = (lane >> 4) * 8, q4 = (lane >> 4) * 4;
    int arow = bb + w * 16 + l15;

    f4_t acc[4] = {};
    #pragma unroll
    for (int ks = 0; ks < 8; ++ks) {
        bf8_t a = *(const bf8_t*)&xb[arow * 256 + ks * 32 + q8];
        #pragma unroll
        for (int gc = 0; gc < 4; ++gc) {
            bf8_t bf = *(const bf8_t*)&w1b[(gb + gc * 16 + l15) * 256 + ks * 32 + q8];
            acc[gc] = mfma16(a, bf, acc[gc]);
        }
    }
    #pragma unroll
    for (int ks = 0; ks < 8; ++ks) {
        bf8_t a = *(const bf8_t*)&hb[arow * 256 + ks * 32 + q8];
        #pragma unroll
        for (int gc = 0; gc < 4; ++gc) {
            bf8_t bf = *(const bf8_t*)&w2b[(gb + gc * 16 + l15) * 256 + ks * 32 + q8];
            acc[gc] = mfma16(a, bf, acc[gc]);
        }
    }
    #pragma unroll
    for (int gc = 0; gc < 4; ++gc) {
        int g = gb + gc * 16 + l15;
        float bias = b1[g] + b2[g];
        #pragma unroll
        for (int r = 0; r < 4; ++r) {
            int b = bb + w * 16 + q4 + r;
            pre[b * 1280 + g] = acc[gc][r] + bias;
        }
    }
}

// ---------------- kernel 2: fused DND partials, producer/consumer waves -----
// 256 blocks = 128 chunks x 2 b-halves (twins bid/bid^8 -> same XCD, share
// K+V via L2). 512 threads = 8 waves: waves 0-3 CONSUMERS (each 32 b-rows x
// 256 h, pure MFMA/exp), waves 4-7 PRODUCERS (stream fp32 K/V -> normalize/
// convert -> swizzled LDS, split-issue so loads are continuously in flight).
// One s_barrier per tile.
__global__ __launch_bounds__(512, 2) void k_dnd(
    const float* __restrict__ keys, const float* __restrict__ vals,
    const unsigned short* __restrict__ qn,
    unsigned short* __restrict__ opart, float* __restrict__ dpart,
    int L, int CH)
{
    // K0 @0 (32KB) | K1 @32768 | V0 @65536 (32KB) | V1 @98304 | P @131072 (16KB)
    __shared__ __align__(16) char smem[147456];
    unsigned short* Pl = (unsigned short*)(smem + 131072);

    const int t = threadIdx.x;
    const int w = t >> 6;
    const int lane = t & 63;
    const int l15 = lane & 15;
    const int q8 = (lane >> 4) * 8;
    const int q4 = (lane >> 4) * 4;

    const int bid = blockIdx.x;
    const int bhalf = (bid >> 3) & 1;
    const int chunk = (bid & 7) | ((bid >> 4) << 3);
    const int base = chunk * CH;
    int nkeys = L - base;
    if (nkeys > CH) nkeys = CH;
    if (nkeys < 0) nkeys = 0;
    const int nt = (nkeys + 63) >> 6;

    // producer mappings (threads 256..511, pw = w-4 in 0..3)
    const int pw = w - 4;
    const int kr = (lane & 15) + pw * 16;     // K row 0..63
    const int kc = (lane >> 4) * 64;          // K col group (64 floats)
    const int vl = pw * 16;                   // V l-row base (16 rows)
                                              // V h: 4*lane..4*lane+3

    f4_t o[2][16] = {};
    float den[2][4] = {};
    bf8_t qa[2][8];
    f4_t kst[16], vst[16];

    auto issueK = [&](int tt) {
        int krow = base + tt * 64 + kr;
        if (krow >= L) krow = L - 1;
        const float* src = keys + (size_t)krow * 256 + kc;
        #pragma unroll
        for (int i = 0; i < 16; ++i) kst[i] = *(const f4_t*)(src + 4 * i);
    };
    auto issueV = [&](int tt) {
        #pragma unroll
        for (int r = 0; r < 16; ++r) {
            int vrow = base + tt * 64 + vl + r;
            if (vrow >= L) vrow = L - 1;
            vst[r] = *(const f4_t*)&vals[(size_t)vrow * 256 + lane * 4];
        }
    };
    auto convertK = [&](char* kb) {
        float ss = 0.f;
        #pragma unroll
        for (int i = 0; i < 16; ++i)
            ss += kst[i][0]*kst[i][0] + kst[i][1]*kst[i][1]
                + kst[i][2]*kst[i][2] + kst[i][3]*kst[i][3];
        ss += __shfl_xor(ss, 16, 64);
        ss += __shfl_xor(ss, 32, 64);
        float rn = 1.0f / fmaxf(sqrtf(ss), 1e-8f);
        unsigned short* K = (unsigned short*)kb;
        #pragma unroll
        for (int m = 0; m < 8; ++m) {
            us8_t uv;
            #pragma unroll
            for (int d = 0; d < 4; ++d) {
                uv[d]     = fbf(kst[2*m][d] * rn);
                uv[d + 4] = fbf(kst[2*m + 1][d] * rn);
            }
            *(us8_t*)&K[kr * 256 + ((kc + 8*m) ^ ((kr & 7) * 8))] = uv;
        }
    };
    auto convertV = [&](char* vb) {
        unsigned short* V = (unsigned short*)vb;
        #pragma unroll
        for (int j = 0; j < 4; ++j) {
            int hh = lane * 4 + j;
            int sp = ((hh >> 3) ^ hh) & 7;
            #pragma unroll
            for (int s2 = 0; s2 < 2; ++s2) {
                us8_t uv;
                #pragma unroll
                for (int r = 0; r < 8; ++r) uv[r] = fbf(vst[s2*8 + r][j]);
                *(us8_t*)&V[hh * 64 + ((vl + s2*8) ^ (sp * 8))] = uv;
            }
        }
    };

    if (w < 4) {
        // consumer: resident Q fragments (qn is small, L1/L2-resident)
        #pragma unroll
        for (int bt = 0; bt < 2; ++bt)
            #pragma unroll
            for (int ks = 0; ks < 8; ++ks)
                qa[bt][ks] = *(const bf8_t*)&qn[(bhalf * 128 + w * 32 + bt * 16 + l15) * 256 + ks * 32 + q8];
    }

    if (nt > 0) {
        if (w >= 4) {
            issueK(0); issueV(0);
            asm volatile("s_waitcnt vmcnt(0)" ::: "memory");
            convertK(smem);
            if (nt > 1) issueK(1);
            convertV(smem + 65536);
            if (nt > 1) issueV(1);
            asm volatile("s_waitcnt lgkmcnt(0)" ::: "memory");
        }
        __builtin_amdgcn_s_barrier();

        for (int tt = 0; tt < nt; ++tt) {
            if (w >= 4) {
                // ---- producer: prepare tile tt+1, keep tt+2 in flight ----
                if (tt + 1 < nt) {
                    asm volatile("s_waitcnt vmcnt(0)" ::: "memory");
                    char* kb = smem + ((tt + 1) & 1) * 32768;
                    char* vb = smem + 65536 + ((tt + 1) & 1) * 32768;
                    convertK(kb);
                    if (tt + 2 < nt) issueK(tt + 2);
                    convertV(vb);
                    if (tt + 2 < nt) issueV(tt + 2);
                    asm volatile("s_waitcnt lgkmcnt(0)" ::: "memory");
                }
            } else {
                // ---- consumer: compute tile tt ----
                const unsigned short* Kl = (const unsigned short*)(smem + (tt & 1) * 32768);
                const unsigned short* Vl = (const unsigned short*)(smem + 65536 + (tt & 1) * 32768);

                f4_t s[2][4] = {};
                __builtin_amdgcn_s_setprio(1);
                #pragma unroll
                for (int lc = 0; lc < 4; ++lc) {
                    int l = lc * 16 + l15;
                    int sw = (l & 7) * 8;
                    #pragma unroll
                    for (int ks = 0; ks < 8; ++ks) {
                        bf8_t kf = *(const bf8_t*)&Kl[l * 256 + ((ks * 32 + q8) ^ sw)];
                        s[0][lc] = mfma16(qa[0][ks], kf, s[0][lc]);
                        s[1][lc] = mfma16(qa[1][ks], kf, s[1][lc]);
                    }
                }
                __builtin_amdgcn_s_setprio(0);

                #pragma unroll
                for (int lc = 0; lc < 4; ++lc) {
                    int l = lc * 16 + l15;
                    bool valid = (tt * 64 + l) < nkeys;
                    #pragma unroll
                    for (int bt = 0; bt < 2; ++bt)
                        #pragma unroll
                        for (int r = 0; r < 4; ++r) {
                            float p = valid ? __expf(s[bt][lc][r] - 1.0f) : 0.0f;
                            den[bt][r] += p;
                            int bl = w * 32 + bt * 16 + q4 + r;
                            Pl[bl * 64 + (l ^ ((bl & 7) * 8))] = fbf(p);
                        }
                }

                bf8_t pa[2][2];
                #pragma unroll
                for (int bt = 0; bt < 2; ++bt) {
                    int br = w * 32 + bt * 16 + l15;
                    int swp = (br & 7) * 8;
                    pa[bt][0] = *(const bf8_t*)&Pl[br * 64 + (q8 ^ swp)];
                    pa[bt][1] = *(const bf8_t*)&Pl[br * 64 + ((32 + q8) ^ swp)];
                }
                __builtin_amdgcn_s_setprio(1);
                #pragma unroll
                for (int hc = 0; hc < 16; ++hc) {
                    int hh = hc * 16 + l15;
                    int sp = ((hh >> 3) ^ hh) & 7;
                    bf8_t vf0 = *(const bf8_t*)&Vl[hh * 64 + (q8 ^ (sp * 8))];
                    bf8_t vf1 = *(const bf8_t*)&Vl[hh * 64 + ((32 + q8) ^ (sp * 8))];
                    o[0][hc] = mfma16(pa[0][0], vf0, o[0][hc]);
                    o[0][hc] = mfma16(pa[0][1], vf1, o[0][hc]);
                    o[1][hc] = mfma16(pa[1][0], vf0, o[1][hc]);
                    o[1][hc] = mfma16(pa[1][1], vf1, o[1][hc]);
                }
                __builtin_amdgcn_s_setprio(0);
            }
            __builtin_amdgcn_s_barrier();
        }
    }

    // ---- epilogue: drain, LDS transpose, coalesced stores ----
    asm volatile("s_waitcnt vmcnt(0)" ::: "memory");
    __syncthreads();
    unsigned short* Ol = (unsigned short*)smem;   // [128 b][256 h]
    if (w < 4) {
        #pragma unroll
        for (int bt = 0; bt < 2; ++bt)
            #pragma unroll
            for (int hc = 0; hc < 16; ++hc)
                #pragma unroll
                for (int r = 0; r < 4; ++r)
                    Ol[(w * 32 + bt * 16 + q4 + r) * 256 + hc * 16 + l15] = fbf(o[bt][hc][r]);
    }
    __syncthreads();
    {
        size_t ob = (size_t)(chunk * 2 + bhalf) * 32768;
        #pragma unroll
        for (int it = 0; it < 8; ++it) {
            int off = it * 4096 + t * 8;
            *(us8_t*)&opart[ob + off] = *(const us8_t*)&Ol[off];
        }
    }
    if (w < 4) {
        #pragma unroll
        for (int bt = 0; bt < 2; ++bt)
            #pragma unroll
            for (int r = 0; r < 4; ++r) {
                float d = den[bt][r];
                #pragma unroll
                for (int m = 1; m < 16; m <<= 1) d += __shfl_xor(d, m, 64);
                if (l15 == 0)
                    dpart[chunk * 256 + bhalf * 128 + w * 32 + bt * 16 + q4 + r] = d;
            }
    }
}

// ---------------- kernel 3: reduce partials + LSTM epilogue -----------------
__global__ __launch_bounds__(256) void k_reduce(
    const unsigned short* __restrict__ opart, const float* __restrict__ dpart,
    const float* __restrict__ pre, const float* __restrict__ c_in,
    float* __restrict__ out)
{
    __shared__ float sred[4];
    int b = blockIdx.x, t = threadIdx.x;

    float ds = (t < 128) ? dpart[t * 256 + b] : 0.0f;
    #pragma unroll
    for (int m = 1; m < 64; m <<= 1) ds += __shfl_xor(ds, m, 64);
    if ((t & 63) == 0) sred[t >> 6] = ds;
    __syncthreads();
    float dtot = fmaxf(sred[0] + sred[1] + sred[2] + sred[3], 1e-30f);

    int bh = b >> 7, br = b & 127;
    float n0 = 0.f, n1 = 0.f, n2 = 0.f, n3 = 0.f;
    for (int ck = 0; ck < 128; ck += 4) {
        n0 += bf2f(opart[(size_t)((ck + 0) * 2 + bh) * 32768 + br * 256 + t]);
        n1 += bf2f(opart[(size_t)((ck + 1) * 2 + bh) * 32768 + br * 256 + t]);
        n2 += bf2f(opart[(size_t)((ck + 2) * 2 + bh) * 32768 + br * 256 + t]);
        n3 += bf2f(opart[(size_t)((ck + 3) * 2 + bh) * 32768 + br * 256 + t]);
    }
    float num = (n0 + n1) + (n2 + n3);

    float m = tanhf(num / dtot);
    const float* p = pre + b * 1280;
    float fg = sigf(p[t]);
    float ig = sigf(p[256 + t]);
    float og = sigf(p[512 + t]);
    float rg = sigf(p[768 + t]);
    float cn = tanhf(p[1024 + t]);
    float co = c_in[b * 256 + t];
    float ct = fg * co + ig * cn + rg * m;
    float ht = og * tanhf(ct);
    out[b * 256 + t] = ht;
    out[65536 + b * 256 + t] = ct;
}

// ---------------- launch ----------------------------------------------------
extern "C" void kernel_launch(void* const* d_in, const int* in_sizes, int n_in,
                              void* d_out, int out_size, void* d_ws, size_t ws_size,
                              hipStream_t stream)
{
    const float* x    = (const float*)d_in[0];
    const float* h    = (const float*)d_in[1];
    const float* c    = (const float*)d_in[2];
    const float* W1   = (const float*)d_in[3];
    const float* b1   = (const float*)d_in[4];
    const float* W2   = (const float*)d_in[5];
    const float* b2   = (const float*)d_in[6];
    const float* keys = (const float*)d_in[7];
    const float* vals = (const float*)d_in[8];
    int L = in_sizes[7] / 256;

    int TILES = (L + 128 * 64 - 1) / (128 * 64);   // tiles per chunk
    int CH = TILES * 64;                           // keys per chunk

    char* ws = (char*)d_ws;
    unsigned short* qn    = (unsigned short*)(ws + 0);
    unsigned short* xb    = (unsigned short*)(ws + 131072);
    unsigned short* hb    = (unsigned short*)(ws + 262144);
    unsigned short* w1b   = (unsigned short*)(ws + 393216);
    unsigned short* w2b   = (unsigned short*)(ws + 1048576);
    float*          pre   = (float*)(ws + 1703936);
    float*          dpart = (float*)(ws + 3014656);
    unsigned short* opart = (unsigned short*)(ws + 3145728);

    k_convert<<<dim3(1024), dim3(256), 0, stream>>>(x, h, W1, W2, qn, xb, hb, w1b, w2b);
    k_gates<<<dim3(80), dim3(256), 0, stream>>>(xb, hb, w1b, w2b, b1, b2, pre);
    k_dnd<<<dim3(256), dim3(512), 0, stream>>>(keys, vals, qn, opart, dpart, L, CH);
    k_reduce<<<dim3(256), dim3(256), 0, stream>>>(opart, dpart, pre, c, (float*)d_out);

    (void)n_in; (void)out_size; (void)ws_size;
}

// Round 6
// 117.936 us; speedup vs baseline: 3.9486x; 3.9486x over previous
//
#include <hip/hip_runtime.h>
#include <stdint.h>

typedef float f4_t __attribute__((ext_vector_type(4)));
typedef __bf16 bf8_t __attribute__((ext_vector_type(8)));
typedef unsigned short us4_t __attribute__((ext_vector_type(4)));
typedef unsigned short us8_t __attribute__((ext_vector_type(8)));

static __device__ __forceinline__ unsigned short fbf(float f) {
    __bf16 b = (__bf16)f;
    return *(unsigned short*)&b;
}
static __device__ __forceinline__ float bf2f(unsigned short u) {
    union { uint32_t u; float f; } v; v.u = ((uint32_t)u) << 16;
    return v.f;
}
static __device__ __forceinline__ f4_t mfma16(bf8_t a, bf8_t b, f4_t c) {
    return __builtin_amdgcn_mfma_f32_16x16x32_bf16(a, b, c, 0, 0, 0);
}
static __device__ __forceinline__ float sigf(float x) {
    return 1.0f / (1.0f + __expf(-x));
}

// ---------------- kernel 0: convert x/h/W to bf16, build q-normalized x ----
__global__ __launch_bounds__(256) void k_convert(
    const float* __restrict__ x, const float* __restrict__ h,
    const float* __restrict__ W1, const float* __restrict__ W2,
    unsigned short* __restrict__ qn, unsigned short* __restrict__ xb,
    unsigned short* __restrict__ hb, unsigned short* __restrict__ w1b,
    unsigned short* __restrict__ w2b)
{
    __shared__ float sred[4];
    int bid = blockIdx.x, t = threadIdx.x;
    if (bid < 256) {
        float v = x[bid * 256 + t];
        float ss = v * v;
        #pragma unroll
        for (int m = 1; m < 64; m <<= 1) ss += __shfl_xor(ss, m, 64);
        if ((t & 63) == 0) sred[t >> 6] = ss;
        __syncthreads();
        float tot = sred[0] + sred[1] + sred[2] + sred[3];
        float rn = 1.0f / fmaxf(sqrtf(tot), 1e-8f);
        xb[bid * 256 + t] = fbf(v);
        qn[bid * 256 + t] = fbf(v * rn);
    } else if (bid < 512) {
        int b = bid - 256;
        hb[b * 256 + t] = fbf(h[b * 256 + t]);
    } else {
        int i0 = (bid - 512) * 256 + t;
        for (int i = i0; i < 1280 * 256; i += 512 * 256) {
            w1b[i] = fbf(W1[i]);
            w2b[i] = fbf(W2[i]);
        }
    }
}

// ---------------- kernel 1: preact = x@W1^T + h@W2^T + b1 + b2 --------------
__global__ __launch_bounds__(256) void k_gates(
    const unsigned short* __restrict__ xb, const unsigned short* __restrict__ hb,
    const unsigned short* __restrict__ w1b, const unsigned short* __restrict__ w2b,
    const float* __restrict__ b1, const float* __restrict__ b2,
    float* __restrict__ pre)
{
    int bb = (blockIdx.x & 3) * 64;
    int gb = (blockIdx.x >> 2) * 64;
    int t = threadIdx.x, w = t >> 6, lane = t & 63;
    int l15 = lane & 15, q8 = (lane >> 4) * 8, q4 = (lane >> 4) * 4;
    int arow = bb + w * 16 + l15;

    f4_t acc[4] = {};
    #pragma unroll
    for (int ks = 0; ks < 8; ++ks) {
        bf8_t a = *(const bf8_t*)&xb[arow * 256 + ks * 32 + q8];
        #pragma unroll
        for (int gc = 0; gc < 4; ++gc) {
            bf8_t bf = *(const bf8_t*)&w1b[(gb + gc * 16 + l15) * 256 + ks * 32 + q8];
            acc[gc] = mfma16(a, bf, acc[gc]);
        }
    }
    #pragma unroll
    for (int ks = 0; ks < 8; ++ks) {
        bf8_t a = *(const bf8_t*)&hb[arow * 256 + ks * 32 + q8];
        #pragma unroll
        for (int gc = 0; gc < 4; ++gc) {
            bf8_t bf = *(const bf8_t*)&w2b[(gb + gc * 16 + l15) * 256 + ks * 32 + q8];
            acc[gc] = mfma16(a, bf, acc[gc]);
        }
    }
    #pragma unroll
    for (int gc = 0; gc < 4; ++gc) {
        int g = gb + gc * 16 + l15;
        float bias = b1[g] + b2[g];
        #pragma unroll
        for (int r = 0; r < 4; ++r) {
            int b = bb + w * 16 + q4 + r;
            pre[b * 1280 + g] = acc[gc][r] + bias;
        }
    }
}

// ---------------- kernel 2: fused DND memory partials ------------------------
// 256 blocks = 128 chunks x 2 b-halves (twins bid/bid^8 -> same XCD, share
// K/V via L2). 512 threads, 8 waves, all waves both stage and compute
// (round-3 phase structure). K fp32 is reg-staged and NORMALIZED IN-REGISTER
// (no pre-pass kernel); V reg-staged + in-reg transpose. Double-buffered K+V,
// one barrier per tile; tile t+2 loads issued during tile t's staging block,
// waited (vmcnt 0) in tile t+1 -> always >= 1 full phase of flight.
__global__ __launch_bounds__(512, 1) void k_dnd(
    const float* __restrict__ keys, const float* __restrict__ vals,
    const unsigned short* __restrict__ qn,
    unsigned short* __restrict__ opart, float* __restrict__ dpart,
    int L, int CH)
{
    // K0 @0 | K1 @32768 | V0 @65536 | V1 @98304 | P @131072   (144 KB)
    __shared__ __align__(16) char smem[147456];
    unsigned short* Pl = (unsigned short*)(smem + 131072);

    const int t = threadIdx.x;
    const int w = t >> 6, lane = t & 63;
    const int l15 = lane & 15;
    const int q8 = (lane >> 4) * 8, q4 = (lane >> 4) * 4;

    const int bid = blockIdx.x;
    const int bhalf = (bid >> 3) & 1;
    const int chunk = (bid & 7) | ((bid >> 4) << 3);
    const int base = chunk * CH;
    int nkeys = L - base;
    if (nkeys > CH) nkeys = CH;
    if (nkeys < 0) nkeys = 0;
    const int nt = (nkeys + 63) >> 6;

    // K staging: thread covers row kr, 32 floats in 8 strided f4 chunks
    const int kr = t >> 3;
    const int j8 = t & 7;
    // V staging: thread covers h-rows 4*lane..+3, l-octet w*8..+7

    bf8_t qa[8];
    #pragma unroll
    for (int ks = 0; ks < 8; ++ks)
        qa[ks] = *(const bf8_t*)&qn[(bhalf * 128 + w * 16 + l15) * 256 + ks * 32 + q8];

    f4_t o[16] = {};
    float den[4] = {};
    f4_t kst[8], vst[8];

    auto issueK = [&](int tt) {
        int row = base + tt * 64 + kr;
        if (row >= L) row = L - 1;
        const float* src = keys + (size_t)row * 256;
        #pragma unroll
        for (int m = 0; m < 8; ++m) kst[m] = *(const f4_t*)(src + m * 32 + j8 * 4);
    };
    auto issueV = [&](int tt) {
        #pragma unroll
        for (int r = 0; r < 8; ++r) {
            int row = base + tt * 64 + w * 8 + r;
            if (row >= L) row = L - 1;
            vst[r] = *(const f4_t*)&vals[(size_t)row * 256 + lane * 4];
        }
    };
    auto stage = [&](char* kb, char* vb) {
        // K: row-norm (8-thread shfl reduce), normalize, bf16, swizzled write
        float ss = 0.f;
        #pragma unroll
        for (int m = 0; m < 8; ++m)
            ss += kst[m][0]*kst[m][0] + kst[m][1]*kst[m][1]
                + kst[m][2]*kst[m][2] + kst[m][3]*kst[m][3];
        ss += __shfl_xor(ss, 1, 64);
        ss += __shfl_xor(ss, 2, 64);
        ss += __shfl_xor(ss, 4, 64);
        float rn = 1.0f / fmaxf(sqrtf(ss), 1e-8f);
        unsigned short* K = (unsigned short*)kb;
        #pragma unroll
        for (int m = 0; m < 8; ++m) {
            us4_t uv;
            uv[0] = fbf(kst[m][0]*rn); uv[1] = fbf(kst[m][1]*rn);
            uv[2] = fbf(kst[m][2]*rn); uv[3] = fbf(kst[m][3]*rn);
            int el = m * 32 + j8 * 4;
            *(us4_t*)&K[kr * 256 + (el ^ ((kr & 7) * 8))] = uv;
        }
        // V: in-reg 8x4 transpose, bf16, conflict-uniform swizzled write
        unsigned short* V = (unsigned short*)vb;
        #pragma unroll
        for (int j = 0; j < 4; ++j) {
            int hh = 4 * lane + j;
            int f = ((hh >> 2) ^ hh) & 7;
            us8_t uv;
            #pragma unroll
            for (int r = 0; r < 8; ++r) uv[r] = fbf(vst[r][j]);
            *(us8_t*)&V[hh * 64 + ((w * 8) ^ (f * 8))] = uv;
        }
    };

    if (nt > 0) {
        issueK(0); issueV(0);
        asm volatile("s_waitcnt vmcnt(0)" ::: "memory");
        stage(smem, smem + 65536);
        if (nt > 1) { issueK(1); issueV(1); __builtin_amdgcn_sched_barrier(0); }
        asm volatile("s_waitcnt lgkmcnt(0)\n\ts_barrier" ::: "memory");

        for (int tt = 0; tt < nt; ++tt) {
            const int cur = tt & 1;
            const unsigned short* Kl = (const unsigned short*)(smem + cur * 32768);
            const unsigned short* Vl = (const unsigned short*)(smem + 65536 + cur * 32768);

            // ---- GEMM1: S = Q @ Kn^T (wave: 16 b x 64 l) ----
            f4_t s[4] = {};
            __builtin_amdgcn_s_setprio(1);
            #pragma unroll
            for (int lc = 0; lc < 4; ++lc) {
                int l = lc * 16 + l15;
                int sw = (l & 7) * 8;
                #pragma unroll
                for (int ks = 0; ks < 8; ++ks) {
                    bf8_t kf = *(const bf8_t*)&Kl[l * 256 + ((ks * 32 + q8) ^ sw)];
                    s[lc] = mfma16(qa[ks], kf, s[lc]);
                }
            }
            __builtin_amdgcn_s_setprio(0);

            // ---- p = exp(s - 1) (sims in [-1,1]); den; P -> LDS ----
            #pragma unroll
            for (int lc = 0; lc < 4; ++lc) {
                int l = lc * 16 + l15;
                bool valid = (tt * 64 + l) < nkeys;
                #pragma unroll
                for (int r = 0; r < 4; ++r) {
                    float p = valid ? __expf(s[lc][r] - 1.0f) : 0.0f;
                    den[r] += p;
                    int br = w * 16 + q4 + r;
                    Pl[br * 64 + (l ^ ((br & 7) * 8))] = fbf(p);
                }
            }

            // ---- GEMM2: O += P @ V (wave reads only its own P rows) ----
            {
                int brow = w * 16 + l15;
                int swp = (brow & 7) * 8;
                bf8_t pa0 = *(const bf8_t*)&Pl[brow * 64 + (q8 ^ swp)];
                bf8_t pa1 = *(const bf8_t*)&Pl[brow * 64 + ((32 + q8) ^ swp)];
                __builtin_amdgcn_s_setprio(1);
                #pragma unroll
                for (int hc = 0; hc < 16; ++hc) {
                    int hh = hc * 16 + l15;
                    int fr = (((hh >> 2) ^ hh) & 7) * 8;
                    bf8_t vf0 = *(const bf8_t*)&Vl[hh * 64 + (q8 ^ fr)];
                    bf8_t vf1 = *(const bf8_t*)&Vl[hh * 64 + ((32 + q8) ^ fr)];
                    o[hc] = mfma16(pa0, vf0, o[hc]);
                    o[hc] = mfma16(pa1, vf1, o[hc]);
                }
                __builtin_amdgcn_s_setprio(0);
            }

            // ---- stage tile t+1 -> other buffers; issue t+2 ----
            if (tt + 1 < nt) {
                asm volatile("s_waitcnt vmcnt(0)" ::: "memory");
                stage(smem + (cur ^ 1) * 32768, smem + 65536 + (cur ^ 1) * 32768);
                if (tt + 2 < nt) {
                    issueK(tt + 2); issueV(tt + 2);
                    __builtin_amdgcn_sched_barrier(0);
                }
                asm volatile("s_waitcnt lgkmcnt(0)\n\ts_barrier" ::: "memory");
            }
        }
    }

    // ---- epilogue: LDS transpose -> coalesced 16B/lane stores ----
    __syncthreads();
    unsigned short* Ol = (unsigned short*)smem;   // [128 b][256 h]
    #pragma unroll
    for (int hc = 0; hc < 16; ++hc)
        #pragma unroll
        for (int r = 0; r < 4; ++r)
            Ol[(w * 16 + q4 + r) * 256 + hc * 16 + l15] = fbf(o[hc][r]);
    __syncthreads();
    {
        size_t ob = (size_t)(chunk * 2 + bhalf) * 32768;
        #pragma unroll
        for (int it = 0; it < 8; ++it) {
            int off = it * 4096 + t * 8;
            *(us8_t*)&opart[ob + off] = *(const us8_t*)&Ol[off];
        }
    }
    #pragma unroll
    for (int r = 0; r < 4; ++r) {
        float d = den[r];
        #pragma unroll
        for (int m = 1; m < 16; m <<= 1) d += __shfl_xor(d, m, 64);
        if (l15 == 0)
            dpart[chunk * 256 + bhalf * 128 + w * 16 + q4 + r] = d;
    }
}

// ---------------- kernel 3: reduce partials + LSTM epilogue -----------------
__global__ __launch_bounds__(256) void k_reduce(
    const unsigned short* __restrict__ opart, const float* __restrict__ dpart,
    const float* __restrict__ pre, const float* __restrict__ c_in,
    float* __restrict__ out)
{
    __shared__ float sred[4];
    int b = blockIdx.x, t = threadIdx.x;

    float ds = (t < 128) ? dpart[t * 256 + b] : 0.0f;
    #pragma unroll
    for (int m = 1; m < 64; m <<= 1) ds += __shfl_xor(ds, m, 64);
    if ((t & 63) == 0) sred[t >> 6] = ds;
    __syncthreads();
    float dtot = fmaxf(sred[0] + sred[1] + sred[2] + sred[3], 1e-30f);

    int bh = b >> 7, br = b & 127;
    float n0 = 0.f, n1 = 0.f, n2 = 0.f, n3 = 0.f;
    for (int ck = 0; ck < 128; ck += 4) {
        n0 += bf2f(opart[(size_t)((ck + 0) * 2 + bh) * 32768 + br * 256 + t]);
        n1 += bf2f(opart[(size_t)((ck + 1) * 2 + bh) * 32768 + br * 256 + t]);
        n2 += bf2f(opart[(size_t)((ck + 2) * 2 + bh) * 32768 + br * 256 + t]);
        n3 += bf2f(opart[(size_t)((ck + 3) * 2 + bh) * 32768 + br * 256 + t]);
    }
    float num = (n0 + n1) + (n2 + n3);

    float m = tanhf(num / dtot);
    const float* p = pre + b * 1280;
    float fg = sigf(p[t]);
    float ig = sigf(p[256 + t]);
    float og = sigf(p[512 + t]);
    float rg = sigf(p[768 + t]);
    float cn = tanhf(p[1024 + t]);
    float co = c_in[b * 256 + t];
    float ct = fg * co + ig * cn + rg * m;
    float ht = og * tanhf(ct);
    out[b * 256 + t] = ht;
    out[65536 + b * 256 + t] = ct;
}

// ---------------- launch ----------------------------------------------------
extern "C" void kernel_launch(void* const* d_in, const int* in_sizes, int n_in,
                              void* d_out, int out_size, void* d_ws, size_t ws_size,
                              hipStream_t stream)
{
    const float* x    = (const float*)d_in[0];
    const float* h    = (const float*)d_in[1];
    const float* c    = (const float*)d_in[2];
    const float* W1   = (const float*)d_in[3];
    const float* b1   = (const float*)d_in[4];
    const float* W2   = (const float*)d_in[5];
    const float* b2   = (const float*)d_in[6];
    const float* keys = (const float*)d_in[7];
    const float* vals = (const float*)d_in[8];
    int L = in_sizes[7] / 256;

    int TILES = (L + 128 * 64 - 1) / (128 * 64);   // tiles per chunk
    int CH = TILES * 64;                           // keys per chunk

    char* ws = (char*)d_ws;
    unsigned short* qn    = (unsigned short*)(ws + 0);
    unsigned short* xb    = (unsigned short*)(ws + 131072);
    unsigned short* hb    = (unsigned short*)(ws + 262144);
    unsigned short* w1b   = (unsigned short*)(ws + 393216);
    unsigned short* w2b   = (unsigned short*)(ws + 1048576);
    float*          pre   = (float*)(ws + 1703936);
    float*          dpart = (float*)(ws + 3014656);
    unsigned short* opart = (unsigned short*)(ws + 3145728);

    k_convert<<<dim3(1024), dim3(256), 0, stream>>>(x, h, W1, W2, qn, xb, hb, w1b, w2b);
    k_gates<<<dim3(80), dim3(256), 0, stream>>>(xb, hb, w1b, w2b, b1, b2, pre);
    k_dnd<<<dim3(256), dim3(512), 0, stream>>>(keys, vals, qn, opart, dpart, L, CH);
    k_reduce<<<dim3(256), dim3(256), 0, stream>>>(opart, dpart, pre, c, (float*)d_out);

    (void)n_in; (void)out_size; (void)ws_size;
}

// Round 7
// 99.816 us; speedup vs baseline: 4.6654x; 1.1815x over previous
//
#include <hip/hip_runtime.h>
#include <stdint.h>

typedef float f4_t __attribute__((ext_vector_type(4)));
typedef __bf16 bf8_t __attribute__((ext_vector_type(8)));
typedef unsigned short us4_t __attribute__((ext_vector_type(4)));
typedef unsigned short us8_t __attribute__((ext_vector_type(8)));

static __device__ __forceinline__ unsigned short fbf(float f) {
    __bf16 b = (__bf16)f;
    return *(unsigned short*)&b;
}
static __device__ __forceinline__ float bf2f(unsigned short u) {
    union { uint32_t u; float f; } v; v.u = ((uint32_t)u) << 16;
    return v.f;
}
static __device__ __forceinline__ f4_t mfma16(bf8_t a, bf8_t b, f4_t c) {
    return __builtin_amdgcn_mfma_f32_16x16x32_bf16(a, b, c, 0, 0, 0);
}
static __device__ __forceinline__ float sigf(float x) {
    return 1.0f / (1.0f + __expf(-x));
}
static __device__ __forceinline__ void gload_lds16(const void* g, void* l) {
    __builtin_amdgcn_global_load_lds(
        (const __attribute__((address_space(1))) void*)g,
        (__attribute__((address_space(3))) void*)l, 16, 0, 0);
}

// ---------------- kernel 0: convert x/h/W to bf16, build q-normalized x ----
__global__ __launch_bounds__(256) void k_convert(
    const float* __restrict__ x, const float* __restrict__ h,
    const float* __restrict__ W1, const float* __restrict__ W2,
    unsigned short* __restrict__ qn, unsigned short* __restrict__ xb,
    unsigned short* __restrict__ hb, unsigned short* __restrict__ w1b,
    unsigned short* __restrict__ w2b)
{
    __shared__ float sred[4];
    int bid = blockIdx.x, t = threadIdx.x;
    if (bid < 256) {
        float v = x[bid * 256 + t];
        float ss = v * v;
        #pragma unroll
        for (int m = 1; m < 64; m <<= 1) ss += __shfl_xor(ss, m, 64);
        if ((t & 63) == 0) sred[t >> 6] = ss;
        __syncthreads();
        float tot = sred[0] + sred[1] + sred[2] + sred[3];
        float rn = 1.0f / fmaxf(sqrtf(tot), 1e-8f);
        xb[bid * 256 + t] = fbf(v);
        qn[bid * 256 + t] = fbf(v * rn);
    } else if (bid < 512) {
        int b = bid - 256;
        hb[b * 256 + t] = fbf(h[b * 256 + t]);
    } else {
        int i0 = (bid - 512) * 256 + t;
        for (int i = i0; i < 1280 * 256; i += 512 * 256) {
            w1b[i] = fbf(W1[i]);
            w2b[i] = fbf(W2[i]);
        }
    }
}

// ---------------- kernel 1: preact = x@W1^T + h@W2^T + b1 + b2 --------------
__global__ __launch_bounds__(256) void k_gates(
    const unsigned short* __restrict__ xb, const unsigned short* __restrict__ hb,
    const unsigned short* __restrict__ w1b, const unsigned short* __restrict__ w2b,
    const float* __restrict__ b1, const float* __restrict__ b2,
    float* __restrict__ pre)
{
    int bb = (blockIdx.x & 3) * 64;
    int gb = (blockIdx.x >> 2) * 64;
    int t = threadIdx.x, w = t >> 6, lane = t & 63;
    int l15 = lane & 15, q8 = (lane >> 4) * 8, q4 = (lane >> 4) * 4;
    int arow = bb + w * 16 + l15;

    f4_t acc[4] = {};
    #pragma unroll
    for (int ks = 0; ks < 8; ++ks) {
        bf8_t a = *(const bf8_t*)&xb[arow * 256 + ks * 32 + q8];
        #pragma unroll
        for (int gc = 0; gc < 4; ++gc) {
            bf8_t bf = *(const bf8_t*)&w1b[(gb + gc * 16 + l15) * 256 + ks * 32 + q8];
            acc[gc] = mfma16(a, bf, acc[gc]);
        }
    }
    #pragma unroll
    for (int ks = 0; ks < 8; ++ks) {
        bf8_t a = *(const bf8_t*)&hb[arow * 256 + ks * 32 + q8];
        #pragma unroll
        for (int gc = 0; gc < 4; ++gc) {
            bf8_t bf = *(const bf8_t*)&w2b[(gb + gc * 16 + l15) * 256 + ks * 32 + q8];
            acc[gc] = mfma16(a, bf, acc[gc]);
        }
    }
    #pragma unroll
    for (int gc = 0; gc < 4; ++gc) {
        int g = gb + gc * 16 + l15;
        float bias = b1[g] + b2[g];
        #pragma unroll
        for (int r = 0; r < 4; ++r) {
            int b = bb + w * 16 + q4 + r;
            pre[b * 1280 + g] = acc[gc][r] + bias;
        }
    }
}

// ---------------- kernel 2: fused DND memory partials ------------------------
// 256 blocks = 128 chunks x 2 h-halves (twins bid/bid^8 -> same XCD, K L2-
// shared; V columns disjoint). 512 threads, 8 waves; wave w owns b-rows
// w*32..+31 x 128 h (its half). ALL staging via async global_load_lds of raw
// fp32 (no staging VGPRs, no reg convoy); normalize/bf16/transpose done as a
// tiny LDS->LDS convert. bf16 buffers double-buffered; raw single-buffered.
// 32-key tiles; loads for tile t+1 are in flight through tile t's GEMMs.
__global__ __launch_bounds__(512, 2) void k_dnd(
    const float* __restrict__ keys, const float* __restrict__ vals,
    const unsigned short* __restrict__ qn,
    unsigned short* __restrict__ opart, float* __restrict__ dpart,
    int L, int CH)
{
    // byte offsets in LDS (112 KB total):
    // RAW_K @0 (32KB fp32 [32][256]) | RAW_V @32768 (16KB fp32 [32][128])
    // KB0 @49152, KB1 @65536 (16KB each, bf16 [32][256] swizzled)
    // VB0 @81920, VB1 @90112 (8KB each, bf16 [128 h][32 l] slot-swizzled)
    // PL @98304 (16KB, bf16 [256 b][32 l])
    __shared__ __align__(16) char smem[114688];
    unsigned short* Pl = (unsigned short*)(smem + 98304);

    const int t = threadIdx.x;
    const int w = t >> 6, lane = t & 63;
    const int l15 = lane & 15;
    const int q8 = (lane >> 4) * 8, q4 = (lane >> 4) * 4;

    const int bid = blockIdx.x;
    const int hhalf = (bid >> 3) & 1;
    const int chunk = (bid & 7) | ((bid >> 4) << 3);
    const int base = chunk * CH;
    int nkeys = L - base;
    if (nkeys > CH) nkeys = CH;
    if (nkeys < 0) nkeys = 0;
    const int nt = (nkeys + 31) >> 5;

    // ---- Q fragments: wave's 32 b-rows (qn L2-resident bf16) ----
    bf8_t qa[2][8];
    #pragma unroll
    for (int bt = 0; bt < 2; ++bt)
        #pragma unroll
        for (int ks = 0; ks < 8; ++ks)
            qa[bt][ks] = *(const bf8_t*)&qn[(w * 32 + bt * 16 + l15) * 256 + ks * 32 + q8];

    f4_t o[2][8] = {};
    float den[2][4] = {};

    // ---- async staging of raw fp32 tile (6 gload_lds per wave) ----
    auto issueRaw = [&](int tt) {
        // K: 4 rows x 1KB, rows 4w..4w+3
        #pragma unroll
        for (int i = 0; i < 4; ++i) {
            int lrow = 4 * w + i;
            int row = base + tt * 32 + lrow;
            if (row >= L) row = L - 1;
            gload_lds16(keys + (size_t)row * 256 + lane * 4,
                        smem + lrow * 1024);
        }
        // V: 4 rows x 512B (this block's h-half), 2 calls of 2 rows
        #pragma unroll
        for (int c = 0; c < 2; ++c) {
            int lrow = 4 * w + 2 * c;
            int row = base + tt * 32 + lrow + (lane >> 5);
            if (row >= L) row = L - 1;
            gload_lds16(vals + (size_t)row * 256 + hhalf * 128 + (lane & 31) * 4,
                        smem + 32768 + lrow * 512);
        }
    };

    // ---- LDS->LDS convert: normalize K rows -> bf16 swz; transpose V ----
    auto convert = [&](int buf) {
        unsigned short* Kb = (unsigned short*)(smem + 49152 + buf * 16384);
        unsigned short* Vb = (unsigned short*)(smem + 81920 + buf * 8192);
        const float* Kraw = (const float*)smem;
        const float* Vraw = (const float*)(smem + 32768);
        // K: thread -> row t>>4, 16 floats at (t&15)*16
        {
            int row = t >> 4, c16 = (t & 15) * 16;
            f4_t a0 = *(const f4_t*)&Kraw[row * 256 + c16];
            f4_t a1 = *(const f4_t*)&Kraw[row * 256 + c16 + 4];
            f4_t a2 = *(const f4_t*)&Kraw[row * 256 + c16 + 8];
            f4_t a3 = *(const f4_t*)&Kraw[row * 256 + c16 + 12];
            float ss = a0[0]*a0[0]+a0[1]*a0[1]+a0[2]*a0[2]+a0[3]*a0[3]
                     + a1[0]*a1[0]+a1[1]*a1[1]+a1[2]*a1[2]+a1[3]*a1[3]
                     + a2[0]*a2[0]+a2[1]*a2[1]+a2[2]*a2[2]+a2[3]*a2[3]
                     + a3[0]*a3[0]+a3[1]*a3[1]+a3[2]*a3[2]+a3[3]*a3[3];
            ss += __shfl_xor(ss, 1, 64);
            ss += __shfl_xor(ss, 2, 64);
            ss += __shfl_xor(ss, 4, 64);
            ss += __shfl_xor(ss, 8, 64);
            float rn = 1.0f / fmaxf(sqrtf(ss), 1e-8f);
            int sw = (row & 7) * 8;
            us8_t u0, u1;
            u0[0]=fbf(a0[0]*rn); u0[1]=fbf(a0[1]*rn); u0[2]=fbf(a0[2]*rn); u0[3]=fbf(a0[3]*rn);
            u0[4]=fbf(a1[0]*rn); u0[5]=fbf(a1[1]*rn); u0[6]=fbf(a1[2]*rn); u0[7]=fbf(a1[3]*rn);
            u1[0]=fbf(a2[0]*rn); u1[1]=fbf(a2[1]*rn); u1[2]=fbf(a2[2]*rn); u1[3]=fbf(a2[3]*rn);
            u1[4]=fbf(a3[0]*rn); u1[5]=fbf(a3[1]*rn); u1[6]=fbf(a3[2]*rn); u1[7]=fbf(a3[3]*rn);
            *(us8_t*)&Kb[row * 256 + (c16 ^ sw)]       = u0;
            *(us8_t*)&Kb[row * 256 + ((c16 + 8) ^ sw)] = u1;
        }
        // V: thread -> h = t&127, l-octet oct = t>>7; Vb[h][l] slot-swizzled
        {
            int hh = t & 127, oct = t >> 7;
            us8_t uv;
            #pragma unroll
            for (int r = 0; r < 8; ++r)
                uv[r] = fbf(Vraw[(oct * 8 + r) * 128 + hh]);
            int slot = (((hh & 15) * 4 + oct) ^ ((hh & 14) >> 1));
            *(us8_t*)&Vb[(hh >> 4) * 512 + slot * 8] = uv;
        }
    };

    if (nt > 0) {
        issueRaw(0);
        asm volatile("s_waitcnt vmcnt(0)" ::: "memory");
        __builtin_amdgcn_s_barrier();
        convert(0);
        asm volatile("s_waitcnt lgkmcnt(0)\n\ts_barrier" ::: "memory");
        if (nt > 1) issueRaw(1);

        for (int tt = 0; tt < nt; ++tt) {
            const int cur = tt & 1;
            const unsigned short* Kb = (const unsigned short*)(smem + 49152 + cur * 16384);
            const unsigned short* Vb = (const unsigned short*)(smem + 81920 + cur * 8192);

            // ---- GEMM1: S = Q @ Kn^T (wave: 32 b x 32 l) ----
            f4_t s[2][2] = {};
            __builtin_amdgcn_s_setprio(1);
            #pragma unroll
            for (int lc = 0; lc < 2; ++lc) {
                int l = lc * 16 + l15;
                int sw = (l & 7) * 8;
                #pragma unroll
                for (int ks = 0; ks < 8; ++ks) {
                    bf8_t kf = *(const bf8_t*)&Kb[l * 256 + ((ks * 32 + q8) ^ sw)];
                    s[0][lc] = mfma16(qa[0][ks], kf, s[0][lc]);
                    s[1][lc] = mfma16(qa[1][ks], kf, s[1][lc]);
                }
            }
            __builtin_amdgcn_s_setprio(0);

            // ---- p = exp(s - 1) (sims in [-1,1]); den accum; P -> LDS ----
            #pragma unroll
            for (int lc = 0; lc < 2; ++lc) {
                int l = lc * 16 + l15;
                bool valid = (tt * 32 + l) < nkeys;
                #pragma unroll
                for (int bt = 0; bt < 2; ++bt)
                    #pragma unroll
                    for (int r = 0; r < 4; ++r) {
                        float p = valid ? __expf(s[bt][lc][r] - 1.0f) : 0.0f;
                        den[bt][r] += p;
                        int b = w * 32 + bt * 16 + q4 + r;
                        Pl[b * 32 + l] = fbf(p);
                    }
            }

            // ---- GEMM2: O += P @ V (wave-private P rows; K=32 per inst) ----
            {
                bf8_t pa0 = *(const bf8_t*)&Pl[(w * 32 + l15) * 32 + q8];
                bf8_t pa1 = *(const bf8_t*)&Pl[(w * 32 + 16 + l15) * 32 + q8];
                __builtin_amdgcn_s_setprio(1);
                #pragma unroll
                for (int hc = 0; hc < 8; ++hc) {
                    int hh = hc * 16 + l15;
                    int slot = (((hh & 15) * 4 + (q8 >> 3)) ^ ((hh & 14) >> 1));
                    bf8_t vf = *(const bf8_t*)&Vb[hc * 512 + slot * 8];
                    o[0][hc] = mfma16(pa0, vf, o[0][hc]);
                    o[1][hc] = mfma16(pa1, vf, o[1][hc]);
                }
                __builtin_amdgcn_s_setprio(0);
            }

            // ---- stage: raw(t+1) arrived during GEMMs; convert; issue t+2 ----
            if (tt + 1 < nt) {
                asm volatile("s_waitcnt vmcnt(0)" ::: "memory");
                __builtin_amdgcn_s_barrier();
                convert(cur ^ 1);
                asm volatile("s_waitcnt lgkmcnt(0)\n\ts_barrier" ::: "memory");
                if (tt + 2 < nt) issueRaw(tt + 2);
            }
        }
    }

    // ---- epilogue: drain, LDS transpose, coalesced stores ----
    asm volatile("s_waitcnt vmcnt(0)" ::: "memory");
    __syncthreads();
    unsigned short* Ol = (unsigned short*)smem;   // [256 b][128 h]
    #pragma unroll
    for (int bt = 0; bt < 2; ++bt)
        #pragma unroll
        for (int hc = 0; hc < 8; ++hc)
            #pragma unroll
            for (int r = 0; r < 4; ++r)
                Ol[(w * 32 + bt * 16 + q4 + r) * 128 + hc * 16 + l15] = fbf(o[bt][hc][r]);
    __syncthreads();
    {
        size_t ob = (size_t)(chunk * 2 + hhalf) * 32768;
        #pragma unroll
        for (int it = 0; it < 8; ++it) {
            int off = it * 4096 + t * 8;
            *(us8_t*)&opart[ob + off] = *(const us8_t*)&Ol[off];
        }
    }
    if (hhalf == 0) {
        #pragma unroll
        for (int bt = 0; bt < 2; ++bt)
            #pragma unroll
            for (int r = 0; r < 4; ++r) {
                float d = den[bt][r];
                #pragma unroll
                for (int m = 1; m < 16; m <<= 1) d += __shfl_xor(d, m, 64);
                if (l15 == 0)
                    dpart[chunk * 256 + w * 32 + bt * 16 + q4 + r] = d;
            }
    }
}

// ---------------- kernel 3: reduce partials + LSTM epilogue -----------------
__global__ __launch_bounds__(256) void k_reduce(
    const unsigned short* __restrict__ opart, const float* __restrict__ dpart,
    const float* __restrict__ pre, const float* __restrict__ c_in,
    float* __restrict__ out)
{
    __shared__ float sred[4];
    int b = blockIdx.x, t = threadIdx.x;

    float ds = (t < 128) ? dpart[t * 256 + b] : 0.0f;
    #pragma unroll
    for (int m = 1; m < 64; m <<= 1) ds += __shfl_xor(ds, m, 64);
    if ((t & 63) == 0) sred[t >> 6] = ds;
    __syncthreads();
    float dtot = fmaxf(sred[0] + sred[1] + sred[2] + sred[3], 1e-30f);

    int bh = t >> 7, hcol = t & 127;
    size_t sb = (size_t)b * 128 + hcol + (size_t)bh * 32768;
    float n0 = 0.f, n1 = 0.f, n2 = 0.f, n3 = 0.f;
    for (int ck = 0; ck < 128; ck += 4) {
        n0 += bf2f(opart[(size_t)(ck + 0) * 65536 + sb]);
        n1 += bf2f(opart[(size_t)(ck + 1) * 65536 + sb]);
        n2 += bf2f(opart[(size_t)(ck + 2) * 65536 + sb]);
        n3 += bf2f(opart[(size_t)(ck + 3) * 65536 + sb]);
    }
    float num = (n0 + n1) + (n2 + n3);

    float m = tanhf(num / dtot);
    const float* p = pre + b * 1280;
    float fg = sigf(p[t]);
    float ig = sigf(p[256 + t]);
    float og = sigf(p[512 + t]);
    float rg = sigf(p[768 + t]);
    float cn = tanhf(p[1024 + t]);
    float co = c_in[b * 256 + t];
    float ct = fg * co + ig * cn + rg * m;
    float ht = og * tanhf(ct);
    out[b * 256 + t] = ht;
    out[65536 + b * 256 + t] = ct;
}

// ---------------- launch ----------------------------------------------------
extern "C" void kernel_launch(void* const* d_in, const int* in_sizes, int n_in,
                              void* d_out, int out_size, void* d_ws, size_t ws_size,
                              hipStream_t stream)
{
    const float* x    = (const float*)d_in[0];
    const float* h    = (const float*)d_in[1];
    const float* c    = (const float*)d_in[2];
    const float* W1   = (const float*)d_in[3];
    const float* b1   = (const float*)d_in[4];
    const float* W2   = (const float*)d_in[5];
    const float* b2   = (const float*)d_in[6];
    const float* keys = (const float*)d_in[7];
    const float* vals = (const float*)d_in[8];
    int L = in_sizes[7] / 256;

    // 128 chunks, each a multiple of 32 keys
    int TILES = (L + 128 * 32 - 1) / (128 * 32);
    int CH = TILES * 32;

    char* ws = (char*)d_ws;
    unsigned short* qn    = (unsigned short*)(ws + 0);
    unsigned short* xb    = (unsigned short*)(ws + 131072);
    unsigned short* hb    = (unsigned short*)(ws + 262144);
    unsigned short* w1b   = (unsigned short*)(ws + 393216);
    unsigned short* w2b   = (unsigned short*)(ws + 1048576);
    float*          pre   = (float*)(ws + 1703936);
    float*          dpart = (float*)(ws + 3014656);
    unsigned short* opart = (unsigned short*)(ws + 3145728);

    k_convert<<<dim3(1024), dim3(256), 0, stream>>>(x, h, W1, W2, qn, xb, hb, w1b, w2b);
    k_gates<<<dim3(80), dim3(256), 0, stream>>>(xb, hb, w1b, w2b, b1, b2, pre);
    k_dnd<<<dim3(256), dim3(512), 0, stream>>>(keys, vals, qn, opart, dpart, L, CH);
    k_reduce<<<dim3(256), dim3(256), 0, stream>>>(opart, dpart, pre, c, (float*)d_out);

    (void)n_in; (void)out_size; (void)ws_size;
}